// Round 12
// baseline (505.534 us; speedup 1.0000x reference)
//
#include <hip/hip_runtime.h>

#define B_ 4
#define N_ 16384
#define DIN_ 512
#define H_ 8
#define DH_ 64
#define M_ 32
#define HM_ 256
#define INNER_ 512
#define K2_PARTS 16
#define K2_NIT 32

typedef _Float16 fp16_t;
typedef _Float16 h8 __attribute__((ext_vector_type(8)));
typedef _Float16 h4 __attribute__((ext_vector_type(4)));
typedef float f4 __attribute__((ext_vector_type(4)));

// Fragment-blocked layout: a logical operand Q[R rows][K contraction] is stored as
// tiles of 16 rows x 32 k; tile -> 512 fp16; element (row, k) at lane*8+e where
// lane = (k%32/8)*16 + row%16, e = k%8. A wave reads one fragment as ONE h8 load
// at (tile_base + lane*8) -- perfectly coalesced 1KB, zero LDS, zero barriers.

// XOR swizzle of hm (in 8-elem groups) by n-group for the K1 epilogue LDS tile
__device__ __forceinline__ int swz(int n, int hm) {
  return ((((hm >> 3) ^ ((n >> 3) & 3)) << 3) | (hm & 7));
}

// XOR-swizzled element offset inside the K1 x-tile [64 rows][512 k] (16B-group swz;
// folds row>>3 so the xt column-gather spreads across banks).
__device__ __forceinline__ int xoff(int row, int k) {
  const int g = ((k >> 3) & 56) | (((k >> 3) ^ row ^ (row >> 3)) & 7);
  return row * 512 + (g << 3) + (k & 7);
}

// ---------------- K0: composite logit weights, emitted FRAGMENT-BLOCKED -------------
// Wcb[kt=16][hmt=16][512]: tile (kt,hmt) holds hm rows hmt*16.., k cols kt*32..
__global__ __launch_bounds__(256) void k0_prep(
    const float* __restrict__ Wx, const float* __restrict__ bx,
    const float* __restrict__ Wslice, const float* __restrict__ bslice,
    const float* __restrict__ temperature,
    fp16_t* __restrict__ Wcb, float* __restrict__ bcomp) {
  __shared__ float ws[M_ * DH_];
  const int h = blockIdx.x;
  const int tid = threadIdx.x;
  for (int i = tid; i < M_ * DH_; i += 256) ws[i] = Wslice[i];
  __syncthreads();
  const float invt = 1.0f / temperature[h];
  for (int m = 0; m < M_; ++m) {
    const int hm = h * M_ + m;
    for (int k = tid; k < DIN_; k += 256) {
      float acc = 0.f;
      #pragma unroll 16
      for (int d = 0; d < DH_; ++d)
        acc += ws[m * DH_ + d] * Wx[(size_t)(h * DH_ + d) * DIN_ + k];
      const int tile = (k >> 5) * 16 + (hm >> 4);
      const int ln = (((k >> 3) & 3) << 4) + (hm & 15);
      Wcb[(size_t)tile * 512 + ln * 8 + (k & 7)] = (fp16_t)(acc * invt);
    }
  }
  if (tid < M_) {
    const int m = tid;
    float acc = bslice[m];
    for (int d = 0; d < DH_; ++d) acc += ws[m * DH_ + d] * bx[h * DH_ + d];
    bcomp[h * M_ + m] = acc * invt;
  }
}

// ---------------- K1: logits GEMM + softmax; emits w_blk, wt_blk, xt_blk ------------
// v6: R8 body with __launch_bounds__(512, 4). LDS (64KB -> 2 blocks/CU) is the
// occupancy limiter, so VGPR up to 128 is free; the explicit bound lets the
// allocator actually batch the 16 staging loads (R8/R11 allocated only 64 VGPRs,
// serializing them).
__global__ __launch_bounds__(512, 4) void k1_logits(
    const float* __restrict__ x, const fp16_t* __restrict__ Wcb,
    const float* __restrict__ bcomp, fp16_t* __restrict__ w_blk,
    fp16_t* __restrict__ wt_blk, fp16_t* __restrict__ xt_blk) {
  __shared__ __align__(16) fp16_t smem[64 * 512];   // 65536 B; x-tile, later lt
  fp16_t* lt = smem;            // [64 n][264 hm-swizzled] epilogue tile (aliases x-tile)
  const int tid = threadIdx.x;
  const int lane = tid & 63;
  const int wv = tid >> 6;                      // 0..7
  const int n0 = blockIdx.x * 64;
  const int b = blockIdx.y;
  f4 acc[4][2] = {};
  const float* xb = x + ((size_t)b * N_ + n0) * DIN_;
  const int lrow = lane & 15;
  const int kgq = lane >> 4;                    // k-subgroup 0..3
  // xt-pass constants: waves 0..3 own chunk (rt, nt) of the 32k x 64n iter tile
  const int xt_rt = wv >> 1;                    // 0..1  (k sub-tile of 16)
  const int xt_nt = wv & 1;                     // 0..1  (n sub-tile of 32)
  const int xt_k = xt_rt * 16 + (lane & 15);
  const int xt_nb = xt_nt * 32 + (lane >> 4) * 8;
  const fp16_t* wp = Wcb + (size_t)(wv * 2) * 512 + lane * 8;  // + (kt*16+t)*512

  // ---- stage the whole x tile: batch-issue all 16 global loads, then convert ----
  f4 xv[16];
  #pragma unroll
  for (int i = 0; i < 16; ++i) {
    const int fid = tid + i * 512;
    xv[i] = *(const f4*)(xb + (size_t)(fid >> 7) * DIN_ + (fid & 127) * 4);
  }
  #pragma unroll
  for (int i = 0; i < 16; ++i) {
    const int fid = tid + i * 512;
    h4 hv = {(fp16_t)xv[i].x, (fp16_t)xv[i].y, (fp16_t)xv[i].z, (fp16_t)xv[i].w};
    *(h4*)&smem[xoff(fid >> 7, (fid & 127) * 4)] = hv;
  }
  h8 bfA[2], bfB[2];
  #pragma unroll
  for (int t = 0; t < 2; ++t) {
    bfA[t] = *(const h8*)(wp + (size_t)t * 512);            // kt = 0
    bfB[t] = *(const h8*)(wp + (size_t)(16 + t) * 512);     // kt = 1
  }
  __syncthreads();

  // ---- barrier-free MFMA k-loop, unrolled x2, Wcb prefetch depth 2 ----
  for (int kt = 0; kt < 16; kt += 2) {
    // even iter (kt) uses bfA
    if (wv < 4) {
      h8 tx;
      #pragma unroll
      for (int e = 0; e < 8; ++e)
        tx[e] = smem[xoff(xt_nb + e, kt * 32 + xt_k)];
      *(h8*)(xt_blk + (((size_t)(b * 32 + kt * 2 + xt_rt) * (N_ / 32)) + (n0 >> 5) + xt_nt) * 512 + lane * 8) = tx;
    }
    {
      h8 af[4];
      #pragma unroll
      for (int t = 0; t < 4; ++t)
        af[t] = *(const h8*)&smem[xoff(t * 16 + lrow, kt * 32 + kgq * 8)];
      #pragma unroll
      for (int tn = 0; tn < 4; ++tn)
        #pragma unroll
        for (int tc = 0; tc < 2; ++tc)
          acc[tn][tc] = __builtin_amdgcn_mfma_f32_16x16x32_f16(af[tn], bfA[tc], acc[tn][tc], 0, 0, 0);
    }
    if (kt + 2 < 16) {
      #pragma unroll
      for (int t = 0; t < 2; ++t)
        bfA[t] = *(const h8*)(wp + (size_t)((kt + 2) * 16 + t) * 512);
    }
    // odd iter (kt+1) uses bfB
    if (wv < 4) {
      h8 tx;
      #pragma unroll
      for (int e = 0; e < 8; ++e)
        tx[e] = smem[xoff(xt_nb + e, (kt + 1) * 32 + xt_k)];
      *(h8*)(xt_blk + (((size_t)(b * 32 + (kt + 1) * 2 + xt_rt) * (N_ / 32)) + (n0 >> 5) + xt_nt) * 512 + lane * 8) = tx;
    }
    {
      h8 af[4];
      #pragma unroll
      for (int t = 0; t < 4; ++t)
        af[t] = *(const h8*)&smem[xoff(t * 16 + lrow, (kt + 1) * 32 + kgq * 8)];
      #pragma unroll
      for (int tn = 0; tn < 4; ++tn)
        #pragma unroll
        for (int tc = 0; tc < 2; ++tc)
          acc[tn][tc] = __builtin_amdgcn_mfma_f32_16x16x32_f16(af[tn], bfB[tc], acc[tn][tc], 0, 0, 0);
    }
    if (kt + 3 < 16) {
      #pragma unroll
      for (int t = 0; t < 2; ++t)
        bfB[t] = *(const h8*)(wp + (size_t)((kt + 3) * 16 + t) * 512);
    }
  }
  __syncthreads();   // all x-tile reads done before lt reuse

  // ---- epilogue: bias-add, dump logits to LDS tile [n][hm] (swizzled) ----
  const int col = lane & 15;
  const int rgrp = (lane >> 4) * 4;
  const float bc0 = bcomp[wv * 32 + col];
  const float bc1 = bcomp[wv * 32 + 16 + col];
  const int hmA = wv * 32 + col;
  #pragma unroll
  for (int tn = 0; tn < 4; ++tn)
    #pragma unroll
    for (int r = 0; r < 4; ++r) {
      const int nl = tn * 16 + rgrp + r;
      lt[nl * 264 + swz(nl, hmA)] = (fp16_t)(acc[tn][0][r] + bc0);
      lt[nl * 264 + swz(nl, hmA + 16)] = (fp16_t)(acc[tn][1][r] + bc1);
    }
  __syncthreads();

  // ---- softmax: each thread owns one (n, head) row of 32 logits ----
  {
    const int nl = tid >> 3, h = tid & 7;
    const int sw = (nl >> 3) & 3;
    h8 ch[4];
    #pragma unroll
    for (int q = 0; q < 4; ++q)
      ch[q] = *(const h8*)&lt[nl * 264 + ((h * 4 + q) ^ sw) * 8];
    float v[32];
    #pragma unroll
    for (int q = 0; q < 4; ++q)
      #pragma unroll
      for (int e = 0; e < 8; ++e) v[q * 8 + e] = (float)ch[q][e];
    float mx = v[0];
    #pragma unroll
    for (int j = 1; j < 32; ++j) mx = fmaxf(mx, v[j]);
    float sm = 0.f;
    #pragma unroll
    for (int j = 0; j < 32; ++j) { v[j] = __expf(v[j] - mx); sm += v[j]; }
    const float inv = __builtin_amdgcn_rcpf(sm);
    h8 oc[4];
    #pragma unroll
    for (int q = 0; q < 4; ++q)
      #pragma unroll
      for (int e = 0; e < 8; ++e) oc[q][e] = (fp16_t)(v[q * 8 + e] * inv);
    #pragma unroll
    for (int q = 0; q < 4; ++q)
      *(h8*)&lt[nl * 264 + ((h * 4 + q) ^ sw) * 8] = oc[q];
  }
  __syncthreads();

  // ---- w_blk pass: contiguous h8 LDS reads -> blocked global (K4 A layout) ----
  #pragma unroll
  for (int p = 0; p < 4; ++p) {
    const int tile = p * 8 + wv;          // 0..31 = 4 ntiles x 8 hmblks
    const int nt_l = tile >> 3, hmb = tile & 7;
    const int n_l = nt_l * 16 + (lane & 15);
    const int g = hmb * 4 + (lane >> 4);
    const int sw = (n_l >> 3) & 3;
    h8 v = *(const h8*)&lt[n_l * 264 + (g ^ sw) * 8];
    *(h8*)(w_blk + (((size_t)(b * (N_ / 16) + (n0 >> 4) + nt_l)) * 8 + hmb) * 512 + lane * 8) = v;
  }

  // ---- wt_blk pass: strided LDS gather -> blocked global (K2 A layout) ----
  #pragma unroll
  for (int p = 0; p < 4; ++p) {
    const int tile = p * 8 + wv;          // 0..31 = 16 hmtiles x 2 ntiles
    const int hmt = tile >> 1, ntl = tile & 1;
    const int hm = hmt * 16 + (lane & 15);
    const int nb = ntl * 32 + (lane >> 4) * 8;
    h8 v;
    #pragma unroll
    for (int e = 0; e < 8; ++e) {
      const int n = nb + e;
      v[e] = lt[n * 264 + swz(n, hm)];
    }
    *(h8*)(wt_blk + (((size_t)(b * 16 + hmt)) * (N_ / 32) + (n0 >> 5) + ntl) * 512 + lane * 8) = v;
  }
}

// ---------------- K2: P[part,b,hm,k] = partial sum_n w^T x — no atomics -------------
// v2 body (best verified, R8); grid TRANSPOSED to (part, combo, b) so blocks
// sharing wt rows (dID +32) and xt rows (dID +16) round-robin onto the SAME XCD
// (delta % 8 == 0) -> second read hits local L2.
__global__ __launch_bounds__(512) void k2_S(
    const fp16_t* __restrict__ wt_blk, const fp16_t* __restrict__ xt_blk,
    float* __restrict__ P, float* __restrict__ norm) {
  const int tid = threadIdx.x, lane = tid & 63, wv = tid >> 6;   // wv 0..7
  const int part = blockIdx.x;
  const int hm0 = (blockIdx.y & 1) * 128;
  const int kc0 = (blockIdx.y >> 1) * 256;
  const int nt0 = part * K2_NIT;              // K2_NIT n-tiles of 32 per block
  const int b = blockIdx.z;
  const int hmw = (wv & 1) * 64, kw = (wv >> 1) * 64;   // kw 0..192
  const int hmt0 = (hm0 + hmw) >> 4;
  const int kt0 = (kc0 + kw) >> 4;
  const fp16_t* ap = wt_blk + (((size_t)(b * 16 + hmt0)) * (N_ / 32) + nt0) * 512 + lane * 8;
  const fp16_t* bp = xt_blk + (((size_t)(b * 32 + kt0)) * (N_ / 32) + nt0) * 512 + lane * 8;
  const size_t arow = (size_t)(N_ / 32) * 512;  // stride between row-tiles
  f4 acc[4][4] = {};
  float ns[4] = {0.f, 0.f, 0.f, 0.f};
  const bool do_norm = (kc0 == 0) && (kw == 0);

  h8 aA[4], bA[4], aB[4], bB[4];
  #pragma unroll
  for (int t = 0; t < 4; ++t) {
    aA[t] = *(const h8*)(ap + (size_t)t * arow);
    bA[t] = *(const h8*)(bp + (size_t)t * arow);
  }
  for (int it = 0; it < K2_NIT; it += 2) {
    #pragma unroll
    for (int t = 0; t < 4; ++t) {
      aB[t] = *(const h8*)(ap + (size_t)t * arow + (it + 1) * 512);
      bB[t] = *(const h8*)(bp + (size_t)t * arow + (it + 1) * 512);
    }
    #pragma unroll
    for (int tn = 0; tn < 4; ++tn)
      #pragma unroll
      for (int tc = 0; tc < 4; ++tc)
        acc[tn][tc] = __builtin_amdgcn_mfma_f32_16x16x32_f16(aA[tn], bA[tc], acc[tn][tc], 0, 0, 0);
    if (do_norm) {
      #pragma unroll
      for (int t = 0; t < 4; ++t)
        #pragma unroll
        for (int e = 0; e < 8; ++e) ns[t] += (float)aA[t][e];
    }
    if (it + 2 < K2_NIT) {
      #pragma unroll
      for (int t = 0; t < 4; ++t) {
        aA[t] = *(const h8*)(ap + (size_t)t * arow + (it + 2) * 512);
        bA[t] = *(const h8*)(bp + (size_t)t * arow + (it + 2) * 512);
      }
    }
    #pragma unroll
    for (int tn = 0; tn < 4; ++tn)
      #pragma unroll
      for (int tc = 0; tc < 4; ++tc)
        acc[tn][tc] = __builtin_amdgcn_mfma_f32_16x16x32_f16(aB[tn], bB[tc], acc[tn][tc], 0, 0, 0);
    if (do_norm) {
      #pragma unroll
      for (int t = 0; t < 4; ++t)
        #pragma unroll
        for (int e = 0; e < 8; ++e) ns[t] += (float)aB[t][e];
    }
  }

  if (do_norm) {
    #pragma unroll
    for (int t = 0; t < 4; ++t) {
      ns[t] += __shfl_xor(ns[t], 16);
      ns[t] += __shfl_xor(ns[t], 32);
    }
    if (lane < 16) {
      #pragma unroll
      for (int t = 0; t < 4; ++t)
        atomicAdd(&norm[b * HM_ + (hmt0 + t) * 16 + lane], ns[t]);
    }
  }
  // plain stores to the partials buffer (this block exclusively owns its cells)
  float* Pp = P + (((size_t)part * B_ + b) * HM_ + hm0 + hmw) * DIN_ + kc0 + kw;
  const int rg = (lane >> 4) * 4;
  #pragma unroll
  for (int tn = 0; tn < 4; ++tn)
    #pragma unroll
    for (int tc = 0; tc < 4; ++tc)
      #pragma unroll
      for (int r = 0; r < 4; ++r)
        Pp[(size_t)(tn * 16 + rg + r) * DIN_ + tc * 16 + (lane & 15)] = acc[tn][tc][r];
}

// ---------------- K2r: S = sum over 16 parts of P -----------------------------------
__global__ __launch_bounds__(256) void k2r_reduce(
    const float* __restrict__ P, float* __restrict__ S) {
  const size_t idx = (size_t)blockIdx.x * 256 + threadIdx.x;   // f4 index
  const f4* P4 = (const f4*)P;
  f4 a = P4[idx];
  #pragma unroll
  for (int p = 1; p < K2_PARTS; ++p)
    a += P4[(size_t)p * (B_ * HM_ * DIN_ / 4) + idx];
  ((f4*)S)[idx] = a;
}

// ---------------- K3a: slice_token[b,h,m,d] = (S.Wfx + bfx*norm)/(norm+1e-5) --------
__global__ __launch_bounds__(256) void k3a_st(
    const float* __restrict__ S, const float* __restrict__ Wfx,
    const float* __restrict__ bfx, const float* __restrict__ norm,
    float* __restrict__ st) {
  const int mq = blockIdx.x;
  const int h = blockIdx.y;
  const int b = blockIdx.z;
  const int tid = threadIdx.x;
  const int m = mq * 4 + (tid >> 6);
  const int d = tid & 63;
  const float* sr = S + ((size_t)b * HM_ + h * M_ + m) * DIN_;
  const float* wr = Wfx + (size_t)(h * DH_ + d) * DIN_;
  float acc = 0.f;
  #pragma unroll 8
  for (int k = 0; k < DIN_; k += 4) {
    f4 a = *(const f4*)(sr + k);
    f4 bb = *(const f4*)(wr + k);
    acc += a.x * bb.x + a.y * bb.y + a.z * bb.z + a.w * bb.w;
  }
  const float nr = norm[b * HM_ + h * M_ + m];
  st[(((size_t)b * H_ + h) * M_ + m) * DH_ + d] =
      (acc + bfx[h * DH_ + d] * nr) / (nr + 1e-5f);
}

// ---------------- K3b: tiny M=32 attention per (b,h) --------------------------------
__global__ __launch_bounds__(256) void k3b_attn(
    const float* __restrict__ st_g, const float* __restrict__ Wq,
    const float* __restrict__ Wk, const float* __restrict__ Wv,
    float* __restrict__ os_g) {
  __shared__ float st[32][65], qs[32][65], ks[32][65], vs[32][65], at[32][33];
  const int h = blockIdx.x, b = blockIdx.y, tid = threadIdx.x;
  const float* stp = st_g + ((size_t)b * H_ + h) * M_ * DH_;
  for (int i = tid; i < 2048; i += 256) st[i >> 6][i & 63] = stp[i];
  __syncthreads();
  for (int i = tid; i < 2048; i += 256) {
    const int m = i >> 6, d = i & 63;
    float aq = 0, ak = 0, av = 0;
    #pragma unroll 8
    for (int dd = 0; dd < 64; ++dd) {
      const float s = st[m][dd];
      aq += s * Wq[d * 64 + dd];
      ak += s * Wk[d * 64 + dd];
      av += s * Wv[d * 64 + dd];
    }
    qs[m][d] = aq; ks[m][d] = ak; vs[m][d] = av;
  }
  __syncthreads();
  for (int i = tid; i < 1024; i += 256) {
    const int m = i >> 5, j = i & 31;
    float a = 0;
    #pragma unroll 8
    for (int d = 0; d < 64; ++d) a += qs[m][d] * ks[j][d];
    at[m][j] = a * 0.125f;
  }
  __syncthreads();
  if (tid < 32) {
    const int m = tid;
    float mx = -1e30f;
    for (int j = 0; j < 32; ++j) mx = fmaxf(mx, at[m][j]);
    float sm = 0;
    for (int j = 0; j < 32; ++j) { const float e = __expf(at[m][j] - mx); at[m][j] = e; sm += e; }
    const float inv = 1.0f / sm;
    for (int j = 0; j < 32; ++j) at[m][j] *= inv;
  }
  __syncthreads();
  float* osp = os_g + ((size_t)b * H_ + h) * M_ * DH_;
  for (int i = tid; i < 2048; i += 256) {
    const int m = i >> 6, d = i & 63;
    float a = 0;
    #pragma unroll 8
    for (int j = 0; j < 32; ++j) a += at[m][j] * vs[j][d];
    osp[i] = a;
  }
}

// ---------------- K3c: Ct_blk[b][kkt=32][hmb=8][512]  (K4 B-operand layout) ---------
__global__ __launch_bounds__(256) void k3c_ct(
    const float* __restrict__ os_g, const float* __restrict__ Wout,
    fp16_t* __restrict__ Ct_blk) {
  const int tid = threadIdx.x, lane = tid & 63, wv = tid >> 6;
  const int b = blockIdx.y;
  const int ti = blockIdx.x * 4 + wv;     // 0..255 tiles
  const int kkt = ti >> 3, hmb = ti & 7;
  const int kk = kkt * 16 + (lane & 15);
  h8 outv;
  #pragma unroll
  for (int e = 0; e < 8; ++e) {
    const int hm = hmb * 32 + (lane >> 4) * 8 + e;
    const int h = hm >> 5, m = hm & 31;
    const float* op = os_g + (((size_t)b * H_ + h) * M_ + m) * DH_;
    const float* wp = Wout + (size_t)kk * INNER_ + h * DH_;
    float acc = 0.f;
    #pragma unroll
    for (int d = 0; d < 64; d += 4) {
      f4 a = *(const f4*)(op + d);
      f4 w4 = *(const f4*)(wp + d);
      acc += a.x * w4.x + a.y * w4.y + a.z * w4.z + a.w * w4.w;
    }
    outv[e] = (fp16_t)acc;
  }
  *(h8*)(Ct_blk + (((size_t)(b * 32 + kkt)) * 8 + hmb) * 512 + lane * 8) = outv;
}

// ---------------- K4: out = w . Ct^T + bout — streaming MFMA ------------------------
// v2 body (best verified, R8); grid TRANSPOSED to (n, kk, b) so the two blocks
// sharing each w_blk panel differ by dID=128 (==0 mod 8) -> same XCD L2.
__global__ __launch_bounds__(512) void k4_out(
    const fp16_t* __restrict__ w_blk, const fp16_t* __restrict__ Ct_blk,
    const float* __restrict__ bout, float* __restrict__ out) {
  const int tid = threadIdx.x, lane = tid & 63, wv = tid >> 6;   // wv 0..7
  const int n0 = blockIdx.x * 128;
  const int kk0 = blockIdx.y * 256;
  const int b = blockIdx.z;
  const int nh = (wv & 1) * 64, kh = (wv >> 1) * 64;   // kh 0..192
  const int nt0 = (n0 + nh) >> 4;
  const int kkt0 = (kk0 + kh) >> 4;
  const fp16_t* ap = w_blk + ((size_t)(b * (N_ / 16) + nt0)) * 8 * 512 + lane * 8;
  const fp16_t* bp = Ct_blk + ((size_t)(b * 32 + kkt0)) * 8 * 512 + lane * 8;
  f4 acc[4][4] = {};

  #pragma unroll
  for (int hmb = 0; hmb < 8; ++hmb) {
    h8 af[4], bf[4];
    #pragma unroll
    for (int t = 0; t < 4; ++t) af[t] = *(const h8*)(ap + (size_t)t * 8 * 512 + hmb * 512);
    #pragma unroll
    for (int t = 0; t < 4; ++t) bf[t] = *(const h8*)(bp + (size_t)t * 8 * 512 + hmb * 512);
    #pragma unroll
    for (int tn = 0; tn < 4; ++tn)
      #pragma unroll
      for (int tc = 0; tc < 4; ++tc)
        acc[tn][tc] = __builtin_amdgcn_mfma_f32_16x16x32_f16(af[tn], bf[tc], acc[tn][tc], 0, 0, 0);
  }
  const int rg = (lane >> 4) * 4;
  #pragma unroll
  for (int tc = 0; tc < 4; ++tc) {
    const int kk = kk0 + kh + tc * 16 + (lane & 15);
    const float bo = bout[kk];
    #pragma unroll
    for (int tn = 0; tn < 4; ++tn)
      #pragma unroll
      for (int r = 0; r < 4; ++r) {
        const int n = n0 + nh + tn * 16 + rg + r;
        out[((size_t)b * N_ + n) * DIN_ + kk] = acc[tn][tc][r] + bo;
      }
  }
}

extern "C" void kernel_launch(void* const* d_in, const int* in_sizes, int n_in,
                              void* d_out, int out_size, void* d_ws, size_t ws_size,
                              hipStream_t stream) {
  (void)in_sizes; (void)n_in; (void)out_size; (void)ws_size;
  const float* x       = (const float*)d_in[0];
  const float* Wx      = (const float*)d_in[1];
  const float* bx      = (const float*)d_in[2];
  const float* Wfx     = (const float*)d_in[3];
  const float* bfx     = (const float*)d_in[4];
  const float* Wslice  = (const float*)d_in[5];
  const float* bslice  = (const float*)d_in[6];
  const float* Wq      = (const float*)d_in[7];
  const float* Wk      = (const float*)d_in[8];
  const float* Wv      = (const float*)d_in[9];
  const float* Wout    = (const float*)d_in[10];
  const float* bout    = (const float*)d_in[11];
  const float* temp    = (const float*)d_in[12];
  float* out = (float*)d_out;

  char* ws = (char*)d_ws;
  fp16_t* w_blk  = (fp16_t*)ws;                    //  33,554,432 : w  blocked (K4-A)
  fp16_t* wt_blk = (fp16_t*)(ws + 33554432);       //  33,554,432 : w^T blocked (K2-A)
  fp16_t* xt_blk = (fp16_t*)(ws + 67108864);       //  67,108,864 : x^T fp16 blocked (K2-B)
  float*  S      = (float*)(ws + 134217728);       //   2,097,152
  float*  norm   = (float*)(ws + 136314880);       //       4,096
  float*  st     = (float*)(ws + 136318976);       //     262,144
  float*  os     = (float*)(ws + 136581120);       //     262,144
  fp16_t* Ct_blk = (fp16_t*)(ws + 136843264);      //   1,048,576
  fp16_t* Wcb    = (fp16_t*)(ws + 137891840);      //     262,144 : Wcomp fragment-blocked
  float*  bcomp  = (float*)(ws + 138153984);       //       4,096 (1KB used)
  float*  P      = (float*)(ws + 138158080);       //  33,554,432 : K2 fp32 partials

  hipMemsetAsync(norm, 0, (size_t)B_ * HM_ * 4, stream);
  k0_prep<<<dim3(H_), 256, 0, stream>>>(Wx, bx, Wslice, bslice, temp, Wcb, bcomp);
  k1_logits<<<dim3(N_ / 64, B_), 512, 0, stream>>>(x, Wcb, bcomp, w_blk, wt_blk, xt_blk);
  k2_S<<<dim3(K2_PARTS, 4, B_), 512, 0, stream>>>(wt_blk, xt_blk, P, norm);
  k2r_reduce<<<dim3(B_ * HM_ * DIN_ / 4 / 256), 256, 0, stream>>>(P, S);
  k3a_st<<<dim3(8, H_, B_), 256, 0, stream>>>(S, Wfx, bfx, norm, st);
  k3b_attn<<<dim3(H_, B_), 256, 0, stream>>>(st, Wq, Wk, Wv, os);
  k3c_ct<<<dim3(64, B_), 256, 0, stream>>>(os, Wout, Ct_blk);
  k4_out<<<dim3(N_ / 128, DIN_ / 256, B_), 512, 0, stream>>>(w_blk, Ct_blk, bout, out);
}

// Round 13
// 448.793 us; speedup vs baseline: 1.1264x; 1.1264x over previous
//
#include <hip/hip_runtime.h>

#define B_ 4
#define N_ 16384
#define DIN_ 512
#define H_ 8
#define DH_ 64
#define M_ 32
#define HM_ 256
#define INNER_ 512
#define K2_PARTS 16
#define K2_NIT 32

typedef _Float16 fp16_t;
typedef _Float16 h8 __attribute__((ext_vector_type(8)));
typedef _Float16 h4 __attribute__((ext_vector_type(4)));
typedef float f4 __attribute__((ext_vector_type(4)));

// Fragment-blocked layout: a logical operand Q[R rows][K contraction] is stored as
// tiles of 16 rows x 32 k; tile -> 512 fp16; element (row, k) at lane*8+e where
// lane = (k%32/8)*16 + row%16, e = k%8. A wave reads one fragment as ONE h8 load
// at (tile_base + lane*8) -- perfectly coalesced 1KB, zero LDS, zero barriers.

// XOR swizzle of hm (in 8-elem groups) by n-group for the K1 epilogue LDS tile
__device__ __forceinline__ int swz(int n, int hm) {
  return ((((hm >> 3) ^ ((n >> 3) & 3)) << 3) | (hm & 7));
}

// XOR-swizzled element offset inside the K1 x-tile [64 rows][512 k] (16B-group swz;
// folds row>>3 so the xt column-gather spreads across banks).
__device__ __forceinline__ int xoff(int row, int k) {
  const int g = ((k >> 3) & 56) | (((k >> 3) ^ row ^ (row >> 3)) & 7);
  return row * 512 + (g << 3) + (k & 7);
}

// ---------------- K0: composite logit weights, emitted FRAGMENT-BLOCKED -------------
// v2: parallelized 8 -> 128 blocks (grid (H,16), 16 k-chunks of 32). The 8-block
// original left 248 CUs idle for the whole dispatch.
__global__ __launch_bounds__(256) void k0_prep(
    const float* __restrict__ Wx, const float* __restrict__ bx,
    const float* __restrict__ Wslice, const float* __restrict__ bslice,
    const float* __restrict__ temperature,
    fp16_t* __restrict__ Wcb, float* __restrict__ bcomp) {
  __shared__ float ws[M_ * DH_];
  const int h = blockIdx.x;
  const int kc = blockIdx.y;                  // k-chunk of 32
  const int tid = threadIdx.x;
  for (int i = tid; i < M_ * DH_; i += 256) ws[i] = Wslice[i];
  __syncthreads();
  const float invt = 1.0f / temperature[h];
  #pragma unroll
  for (int j = 0; j < 4; ++j) {
    const int idx = tid + j * 256;            // 0..1023 = 32 m x 32 k
    const int m = idx >> 5;
    const int k = kc * 32 + (idx & 31);
    const int hm = h * M_ + m;
    float acc = 0.f;
    #pragma unroll 16
    for (int d = 0; d < DH_; ++d)
      acc += ws[m * DH_ + d] * Wx[(size_t)(h * DH_ + d) * DIN_ + k];
    const int tile = (k >> 5) * 16 + (hm >> 4);
    const int ln = (((k >> 3) & 3) << 4) + (hm & 15);
    Wcb[(size_t)tile * 512 + ln * 8 + (k & 7)] = (fp16_t)(acc * invt);
  }
  if (kc == 0 && tid < M_) {
    const int m = tid;
    float acc = bslice[m];
    for (int d = 0; d < DH_; ++d) acc += ws[m * DH_ + d] * bx[h * DH_ + d];
    bcomp[h * M_ + m] = acc * invt;
  }
}

// ---------------- K1: logits GEMM + softmax; emits w_blk, wt_blk, xt_blk ------------
// v4 (best verified, R8/R11): 512 threads / 8 waves; 64KB x-tile staged once (batch
// loads); barrier-free k-loop unrolled x2 with depth-2 Wcb prefetch.
__global__ __launch_bounds__(512) void k1_logits(
    const float* __restrict__ x, const fp16_t* __restrict__ Wcb,
    const float* __restrict__ bcomp, fp16_t* __restrict__ w_blk,
    fp16_t* __restrict__ wt_blk, fp16_t* __restrict__ xt_blk) {
  __shared__ __align__(16) fp16_t smem[64 * 512];   // 65536 B; x-tile, later lt
  fp16_t* lt = smem;            // [64 n][264 hm-swizzled] epilogue tile (aliases x-tile)
  const int tid = threadIdx.x;
  const int lane = tid & 63;
  const int wv = tid >> 6;                      // 0..7
  const int n0 = blockIdx.x * 64;
  const int b = blockIdx.y;
  f4 acc[4][2] = {};
  const float* xb = x + ((size_t)b * N_ + n0) * DIN_;
  const int lrow = lane & 15;
  const int kgq = lane >> 4;                    // k-subgroup 0..3
  // xt-pass constants: waves 0..3 own chunk (rt, nt) of the 32k x 64n iter tile
  const int xt_rt = wv >> 1;                    // 0..1  (k sub-tile of 16)
  const int xt_nt = wv & 1;                     // 0..1  (n sub-tile of 32)
  const int xt_k = xt_rt * 16 + (lane & 15);
  const int xt_nb = xt_nt * 32 + (lane >> 4) * 8;
  const fp16_t* wp = Wcb + (size_t)(wv * 2) * 512 + lane * 8;  // + (kt*16+t)*512

  // ---- stage the whole x tile: batch-issue all 16 global loads, then convert ----
  f4 xv[16];
  #pragma unroll
  for (int i = 0; i < 16; ++i) {
    const int fid = tid + i * 512;
    xv[i] = *(const f4*)(xb + (size_t)(fid >> 7) * DIN_ + (fid & 127) * 4);
  }
  #pragma unroll
  for (int i = 0; i < 16; ++i) {
    const int fid = tid + i * 512;
    h4 hv = {(fp16_t)xv[i].x, (fp16_t)xv[i].y, (fp16_t)xv[i].z, (fp16_t)xv[i].w};
    *(h4*)&smem[xoff(fid >> 7, (fid & 127) * 4)] = hv;
  }
  h8 bfA[2], bfB[2];
  #pragma unroll
  for (int t = 0; t < 2; ++t) {
    bfA[t] = *(const h8*)(wp + (size_t)t * 512);            // kt = 0
    bfB[t] = *(const h8*)(wp + (size_t)(16 + t) * 512);     // kt = 1
  }
  __syncthreads();

  // ---- barrier-free MFMA k-loop, unrolled x2, Wcb prefetch depth 2 ----
  for (int kt = 0; kt < 16; kt += 2) {
    // even iter (kt) uses bfA
    if (wv < 4) {
      h8 tx;
      #pragma unroll
      for (int e = 0; e < 8; ++e)
        tx[e] = smem[xoff(xt_nb + e, kt * 32 + xt_k)];
      *(h8*)(xt_blk + (((size_t)(b * 32 + kt * 2 + xt_rt) * (N_ / 32)) + (n0 >> 5) + xt_nt) * 512 + lane * 8) = tx;
    }
    {
      h8 af[4];
      #pragma unroll
      for (int t = 0; t < 4; ++t)
        af[t] = *(const h8*)&smem[xoff(t * 16 + lrow, kt * 32 + kgq * 8)];
      #pragma unroll
      for (int tn = 0; tn < 4; ++tn)
        #pragma unroll
        for (int tc = 0; tc < 2; ++tc)
          acc[tn][tc] = __builtin_amdgcn_mfma_f32_16x16x32_f16(af[tn], bfA[tc], acc[tn][tc], 0, 0, 0);
    }
    if (kt + 2 < 16) {
      #pragma unroll
      for (int t = 0; t < 2; ++t)
        bfA[t] = *(const h8*)(wp + (size_t)((kt + 2) * 16 + t) * 512);
    }
    // odd iter (kt+1) uses bfB
    if (wv < 4) {
      h8 tx;
      #pragma unroll
      for (int e = 0; e < 8; ++e)
        tx[e] = smem[xoff(xt_nb + e, (kt + 1) * 32 + xt_k)];
      *(h8*)(xt_blk + (((size_t)(b * 32 + (kt + 1) * 2 + xt_rt) * (N_ / 32)) + (n0 >> 5) + xt_nt) * 512 + lane * 8) = tx;
    }
    {
      h8 af[4];
      #pragma unroll
      for (int t = 0; t < 4; ++t)
        af[t] = *(const h8*)&smem[xoff(t * 16 + lrow, (kt + 1) * 32 + kgq * 8)];
      #pragma unroll
      for (int tn = 0; tn < 4; ++tn)
        #pragma unroll
        for (int tc = 0; tc < 2; ++tc)
          acc[tn][tc] = __builtin_amdgcn_mfma_f32_16x16x32_f16(af[tn], bfB[tc], acc[tn][tc], 0, 0, 0);
    }
    if (kt + 3 < 16) {
      #pragma unroll
      for (int t = 0; t < 2; ++t)
        bfB[t] = *(const h8*)(wp + (size_t)((kt + 3) * 16 + t) * 512);
    }
  }
  __syncthreads();   // all x-tile reads done before lt reuse

  // ---- epilogue: bias-add, dump logits to LDS tile [n][hm] (swizzled) ----
  const int col = lane & 15;
  const int rgrp = (lane >> 4) * 4;
  const float bc0 = bcomp[wv * 32 + col];
  const float bc1 = bcomp[wv * 32 + 16 + col];
  const int hmA = wv * 32 + col;
  #pragma unroll
  for (int tn = 0; tn < 4; ++tn)
    #pragma unroll
    for (int r = 0; r < 4; ++r) {
      const int nl = tn * 16 + rgrp + r;
      lt[nl * 264 + swz(nl, hmA)] = (fp16_t)(acc[tn][0][r] + bc0);
      lt[nl * 264 + swz(nl, hmA + 16)] = (fp16_t)(acc[tn][1][r] + bc1);
    }
  __syncthreads();

  // ---- softmax: each thread owns one (n, head) row of 32 logits ----
  {
    const int nl = tid >> 3, h = tid & 7;
    const int sw = (nl >> 3) & 3;
    h8 ch[4];
    #pragma unroll
    for (int q = 0; q < 4; ++q)
      ch[q] = *(const h8*)&lt[nl * 264 + ((h * 4 + q) ^ sw) * 8];
    float v[32];
    #pragma unroll
    for (int q = 0; q < 4; ++q)
      #pragma unroll
      for (int e = 0; e < 8; ++e) v[q * 8 + e] = (float)ch[q][e];
    float mx = v[0];
    #pragma unroll
    for (int j = 1; j < 32; ++j) mx = fmaxf(mx, v[j]);
    float sm = 0.f;
    #pragma unroll
    for (int j = 0; j < 32; ++j) { v[j] = __expf(v[j] - mx); sm += v[j]; }
    const float inv = __builtin_amdgcn_rcpf(sm);
    h8 oc[4];
    #pragma unroll
    for (int q = 0; q < 4; ++q)
      #pragma unroll
      for (int e = 0; e < 8; ++e) oc[q][e] = (fp16_t)(v[q * 8 + e] * inv);
    #pragma unroll
    for (int q = 0; q < 4; ++q)
      *(h8*)&lt[nl * 264 + ((h * 4 + q) ^ sw) * 8] = oc[q];
  }
  __syncthreads();

  // ---- w_blk pass: contiguous h8 LDS reads -> blocked global (K4 A layout) ----
  #pragma unroll
  for (int p = 0; p < 4; ++p) {
    const int tile = p * 8 + wv;          // 0..31 = 4 ntiles x 8 hmblks
    const int nt_l = tile >> 3, hmb = tile & 7;
    const int n_l = nt_l * 16 + (lane & 15);
    const int g = hmb * 4 + (lane >> 4);
    const int sw = (n_l >> 3) & 3;
    h8 v = *(const h8*)&lt[n_l * 264 + (g ^ sw) * 8];
    *(h8*)(w_blk + (((size_t)(b * (N_ / 16) + (n0 >> 4) + nt_l)) * 8 + hmb) * 512 + lane * 8) = v;
  }

  // ---- wt_blk pass: strided LDS gather -> blocked global (K2 A layout) ----
  #pragma unroll
  for (int p = 0; p < 4; ++p) {
    const int tile = p * 8 + wv;          // 0..31 = 16 hmtiles x 2 ntiles
    const int hmt = tile >> 1, ntl = tile & 1;
    const int hm = hmt * 16 + (lane & 15);
    const int nb = ntl * 32 + (lane >> 4) * 8;
    h8 v;
    #pragma unroll
    for (int e = 0; e < 8; ++e) {
      const int n = nb + e;
      v[e] = lt[n * 264 + swz(n, hm)];
    }
    *(h8*)(wt_blk + (((size_t)(b * 16 + hmt)) * (N_ / 32) + (n0 >> 5) + ntl) * 512 + lane * 8) = v;
  }
}

// ---------------- K2: P[part,b,hm,k] = partial sum_n w^T x — no atomics -------------
// v2 body (best verified, R8); grid TRANSPOSED to (part, combo, b) so blocks
// sharing wt rows (dID +32) and xt rows (dID +16) round-robin onto the SAME XCD
// (delta % 8 == 0) -> second read hits local L2.
__global__ __launch_bounds__(512) void k2_S(
    const fp16_t* __restrict__ wt_blk, const fp16_t* __restrict__ xt_blk,
    float* __restrict__ P, float* __restrict__ norm) {
  const int tid = threadIdx.x, lane = tid & 63, wv = tid >> 6;   // wv 0..7
  const int part = blockIdx.x;
  const int hm0 = (blockIdx.y & 1) * 128;
  const int kc0 = (blockIdx.y >> 1) * 256;
  const int nt0 = part * K2_NIT;              // K2_NIT n-tiles of 32 per block
  const int b = blockIdx.z;
  const int hmw = (wv & 1) * 64, kw = (wv >> 1) * 64;   // kw 0..192
  const int hmt0 = (hm0 + hmw) >> 4;
  const int kt0 = (kc0 + kw) >> 4;
  const fp16_t* ap = wt_blk + (((size_t)(b * 16 + hmt0)) * (N_ / 32) + nt0) * 512 + lane * 8;
  const fp16_t* bp = xt_blk + (((size_t)(b * 32 + kt0)) * (N_ / 32) + nt0) * 512 + lane * 8;
  const size_t arow = (size_t)(N_ / 32) * 512;  // stride between row-tiles
  f4 acc[4][4] = {};
  float ns[4] = {0.f, 0.f, 0.f, 0.f};
  const bool do_norm = (kc0 == 0) && (kw == 0);

  h8 aA[4], bA[4], aB[4], bB[4];
  #pragma unroll
  for (int t = 0; t < 4; ++t) {
    aA[t] = *(const h8*)(ap + (size_t)t * arow);
    bA[t] = *(const h8*)(bp + (size_t)t * arow);
  }
  for (int it = 0; it < K2_NIT; it += 2) {
    #pragma unroll
    for (int t = 0; t < 4; ++t) {
      aB[t] = *(const h8*)(ap + (size_t)t * arow + (it + 1) * 512);
      bB[t] = *(const h8*)(bp + (size_t)t * arow + (it + 1) * 512);
    }
    #pragma unroll
    for (int tn = 0; tn < 4; ++tn)
      #pragma unroll
      for (int tc = 0; tc < 4; ++tc)
        acc[tn][tc] = __builtin_amdgcn_mfma_f32_16x16x32_f16(aA[tn], bA[tc], acc[tn][tc], 0, 0, 0);
    if (do_norm) {
      #pragma unroll
      for (int t = 0; t < 4; ++t)
        #pragma unroll
        for (int e = 0; e < 8; ++e) ns[t] += (float)aA[t][e];
    }
    if (it + 2 < K2_NIT) {
      #pragma unroll
      for (int t = 0; t < 4; ++t) {
        aA[t] = *(const h8*)(ap + (size_t)t * arow + (it + 2) * 512);
        bA[t] = *(const h8*)(bp + (size_t)t * arow + (it + 2) * 512);
      }
    }
    #pragma unroll
    for (int tn = 0; tn < 4; ++tn)
      #pragma unroll
      for (int tc = 0; tc < 4; ++tc)
        acc[tn][tc] = __builtin_amdgcn_mfma_f32_16x16x32_f16(aB[tn], bB[tc], acc[tn][tc], 0, 0, 0);
    if (do_norm) {
      #pragma unroll
      for (int t = 0; t < 4; ++t)
        #pragma unroll
        for (int e = 0; e < 8; ++e) ns[t] += (float)aB[t][e];
    }
  }

  if (do_norm) {
    #pragma unroll
    for (int t = 0; t < 4; ++t) {
      ns[t] += __shfl_xor(ns[t], 16);
      ns[t] += __shfl_xor(ns[t], 32);
    }
    if (lane < 16) {
      #pragma unroll
      for (int t = 0; t < 4; ++t)
        atomicAdd(&norm[b * HM_ + (hmt0 + t) * 16 + lane], ns[t]);
    }
  }
  // plain stores to the partials buffer (this block exclusively owns its cells)
  float* Pp = P + (((size_t)part * B_ + b) * HM_ + hm0 + hmw) * DIN_ + kc0 + kw;
  const int rg = (lane >> 4) * 4;
  #pragma unroll
  for (int tn = 0; tn < 4; ++tn)
    #pragma unroll
    for (int tc = 0; tc < 4; ++tc)
      #pragma unroll
      for (int r = 0; r < 4; ++r)
        Pp[(size_t)(tn * 16 + rg + r) * DIN_ + tc * 16 + (lane & 15)] = acc[tn][tc][r];
}

// ---------------- K2r: S = sum over 16 parts of P -----------------------------------
__global__ __launch_bounds__(256) void k2r_reduce(
    const float* __restrict__ P, float* __restrict__ S) {
  const size_t idx = (size_t)blockIdx.x * 256 + threadIdx.x;   // f4 index
  const f4* P4 = (const f4*)P;
  f4 a = P4[idx];
  #pragma unroll
  for (int p = 1; p < K2_PARTS; ++p)
    a += P4[(size_t)p * (B_ * HM_ * DIN_ / 4) + idx];
  ((f4*)S)[idx] = a;
}

// ---------------- K3a: slice_token[b,h,m,d] = (S.Wfx + bfx*norm)/(norm+1e-5) --------
__global__ __launch_bounds__(256) void k3a_st(
    const float* __restrict__ S, const float* __restrict__ Wfx,
    const float* __restrict__ bfx, const float* __restrict__ norm,
    float* __restrict__ st) {
  const int mq = blockIdx.x;
  const int h = blockIdx.y;
  const int b = blockIdx.z;
  const int tid = threadIdx.x;
  const int m = mq * 4 + (tid >> 6);
  const int d = tid & 63;
  const float* sr = S + ((size_t)b * HM_ + h * M_ + m) * DIN_;
  const float* wr = Wfx + (size_t)(h * DH_ + d) * DIN_;
  float acc = 0.f;
  #pragma unroll 8
  for (int k = 0; k < DIN_; k += 4) {
    f4 a = *(const f4*)(sr + k);
    f4 bb = *(const f4*)(wr + k);
    acc += a.x * bb.x + a.y * bb.y + a.z * bb.z + a.w * bb.w;
  }
  const float nr = norm[b * HM_ + h * M_ + m];
  st[(((size_t)b * H_ + h) * M_ + m) * DH_ + d] =
      (acc + bfx[h * DH_ + d] * nr) / (nr + 1e-5f);
}

// ---------------- K3b: tiny M=32 attention per (b,h) --------------------------------
__global__ __launch_bounds__(256) void k3b_attn(
    const float* __restrict__ st_g, const float* __restrict__ Wq,
    const float* __restrict__ Wk, const float* __restrict__ Wv,
    float* __restrict__ os_g) {
  __shared__ float st[32][65], qs[32][65], ks[32][65], vs[32][65], at[32][33];
  const int h = blockIdx.x, b = blockIdx.y, tid = threadIdx.x;
  const float* stp = st_g + ((size_t)b * H_ + h) * M_ * DH_;
  for (int i = tid; i < 2048; i += 256) st[i >> 6][i & 63] = stp[i];
  __syncthreads();
  for (int i = tid; i < 2048; i += 256) {
    const int m = i >> 6, d = i & 63;
    float aq = 0, ak = 0, av = 0;
    #pragma unroll 8
    for (int dd = 0; dd < 64; ++dd) {
      const float s = st[m][dd];
      aq += s * Wq[d * 64 + dd];
      ak += s * Wk[d * 64 + dd];
      av += s * Wv[d * 64 + dd];
    }
    qs[m][d] = aq; ks[m][d] = ak; vs[m][d] = av;
  }
  __syncthreads();
  for (int i = tid; i < 1024; i += 256) {
    const int m = i >> 5, j = i & 31;
    float a = 0;
    #pragma unroll 8
    for (int d = 0; d < 64; ++d) a += qs[m][d] * ks[j][d];
    at[m][j] = a * 0.125f;
  }
  __syncthreads();
  if (tid < 32) {
    const int m = tid;
    float mx = -1e30f;
    for (int j = 0; j < 32; ++j) mx = fmaxf(mx, at[m][j]);
    float sm = 0;
    for (int j = 0; j < 32; ++j) { const float e = __expf(at[m][j] - mx); at[m][j] = e; sm += e; }
    const float inv = 1.0f / sm;
    for (int j = 0; j < 32; ++j) at[m][j] *= inv;
  }
  __syncthreads();
  float* osp = os_g + ((size_t)b * H_ + h) * M_ * DH_;
  for (int i = tid; i < 2048; i += 256) {
    const int m = i >> 6, d = i & 63;
    float a = 0;
    #pragma unroll 8
    for (int j = 0; j < 32; ++j) a += at[m][j] * vs[j][d];
    osp[i] = a;
  }
}

// ---------------- K3c: Ct_blk[b][kkt=32][hmb=8][512]  (K4 B-operand layout) ---------
__global__ __launch_bounds__(256) void k3c_ct(
    const float* __restrict__ os_g, const float* __restrict__ Wout,
    fp16_t* __restrict__ Ct_blk) {
  const int tid = threadIdx.x, lane = tid & 63, wv = tid >> 6;
  const int b = blockIdx.y;
  const int ti = blockIdx.x * 4 + wv;     // 0..255 tiles
  const int kkt = ti >> 3, hmb = ti & 7;
  const int kk = kkt * 16 + (lane & 15);
  h8 outv;
  #pragma unroll
  for (int e = 0; e < 8; ++e) {
    const int hm = hmb * 32 + (lane >> 4) * 8 + e;
    const int h = hm >> 5, m = hm & 31;
    const float* op = os_g + (((size_t)b * H_ + h) * M_ + m) * DH_;
    const float* wp = Wout + (size_t)kk * INNER_ + h * DH_;
    float acc = 0.f;
    #pragma unroll
    for (int d = 0; d < 64; d += 4) {
      f4 a = *(const f4*)(op + d);
      f4 w4 = *(const f4*)(wp + d);
      acc += a.x * w4.x + a.y * w4.y + a.z * w4.z + a.w * w4.w;
    }
    outv[e] = (fp16_t)acc;
  }
  *(h8*)(Ct_blk + (((size_t)(b * 32 + kkt)) * 8 + hmb) * 512 + lane * 8) = outv;
}

// ---------------- K4: out = w . Ct^T + bout — streaming MFMA ------------------------
// v2 body (best verified, R8); grid TRANSPOSED to (n, kk, b) so the two blocks
// sharing each w_blk panel differ by dID=128 (==0 mod 8) -> same XCD L2.
__global__ __launch_bounds__(512) void k4_out(
    const fp16_t* __restrict__ w_blk, const fp16_t* __restrict__ Ct_blk,
    const float* __restrict__ bout, float* __restrict__ out) {
  const int tid = threadIdx.x, lane = tid & 63, wv = tid >> 6;   // wv 0..7
  const int n0 = blockIdx.x * 128;
  const int kk0 = blockIdx.y * 256;
  const int b = blockIdx.z;
  const int nh = (wv & 1) * 64, kh = (wv >> 1) * 64;   // kh 0..192
  const int nt0 = (n0 + nh) >> 4;
  const int kkt0 = (kk0 + kh) >> 4;
  const fp16_t* ap = w_blk + ((size_t)(b * (N_ / 16) + nt0)) * 8 * 512 + lane * 8;
  const fp16_t* bp = Ct_blk + ((size_t)(b * 32 + kkt0)) * 8 * 512 + lane * 8;
  f4 acc[4][4] = {};

  #pragma unroll
  for (int hmb = 0; hmb < 8; ++hmb) {
    h8 af[4], bf[4];
    #pragma unroll
    for (int t = 0; t < 4; ++t) af[t] = *(const h8*)(ap + (size_t)t * 8 * 512 + hmb * 512);
    #pragma unroll
    for (int t = 0; t < 4; ++t) bf[t] = *(const h8*)(bp + (size_t)t * 8 * 512 + hmb * 512);
    #pragma unroll
    for (int tn = 0; tn < 4; ++tn)
      #pragma unroll
      for (int tc = 0; tc < 4; ++tc)
        acc[tn][tc] = __builtin_amdgcn_mfma_f32_16x16x32_f16(af[tn], bf[tc], acc[tn][tc], 0, 0, 0);
  }
  const int rg = (lane >> 4) * 4;
  #pragma unroll
  for (int tc = 0; tc < 4; ++tc) {
    const int kk = kk0 + kh + tc * 16 + (lane & 15);
    const float bo = bout[kk];
    #pragma unroll
    for (int tn = 0; tn < 4; ++tn)
      #pragma unroll
      for (int r = 0; r < 4; ++r) {
        const int n = n0 + nh + tn * 16 + rg + r;
        out[((size_t)b * N_ + n) * DIN_ + kk] = acc[tn][tc][r] + bo;
      }
  }
}

extern "C" void kernel_launch(void* const* d_in, const int* in_sizes, int n_in,
                              void* d_out, int out_size, void* d_ws, size_t ws_size,
                              hipStream_t stream) {
  (void)in_sizes; (void)n_in; (void)out_size; (void)ws_size;
  const float* x       = (const float*)d_in[0];
  const float* Wx      = (const float*)d_in[1];
  const float* bx      = (const float*)d_in[2];
  const float* Wfx     = (const float*)d_in[3];
  const float* bfx     = (const float*)d_in[4];
  const float* Wslice  = (const float*)d_in[5];
  const float* bslice  = (const float*)d_in[6];
  const float* Wq      = (const float*)d_in[7];
  const float* Wk      = (const float*)d_in[8];
  const float* Wv      = (const float*)d_in[9];
  const float* Wout    = (const float*)d_in[10];
  const float* bout    = (const float*)d_in[11];
  const float* temp    = (const float*)d_in[12];
  float* out = (float*)d_out;

  char* ws = (char*)d_ws;
  fp16_t* w_blk  = (fp16_t*)ws;                    //  33,554,432 : w  blocked (K4-A)
  fp16_t* wt_blk = (fp16_t*)(ws + 33554432);       //  33,554,432 : w^T blocked (K2-A)
  fp16_t* xt_blk = (fp16_t*)(ws + 67108864);       //  67,108,864 : x^T fp16 blocked (K2-B)
  float*  S      = (float*)(ws + 134217728);       //   2,097,152
  float*  norm   = (float*)(ws + 136314880);       //       4,096
  float*  st     = (float*)(ws + 136318976);       //     262,144
  float*  os     = (float*)(ws + 136581120);       //     262,144
  fp16_t* Ct_blk = (fp16_t*)(ws + 136843264);      //   1,048,576
  fp16_t* Wcb    = (fp16_t*)(ws + 137891840);      //     262,144 : Wcomp fragment-blocked
  float*  bcomp  = (float*)(ws + 138153984);       //       4,096 (1KB used)
  float*  P      = (float*)(ws + 138158080);       //  33,554,432 : K2 fp32 partials

  hipMemsetAsync(norm, 0, (size_t)B_ * HM_ * 4, stream);
  k0_prep<<<dim3(H_, 16), 256, 0, stream>>>(Wx, bx, Wslice, bslice, temp, Wcb, bcomp);
  k1_logits<<<dim3(N_ / 64, B_), 512, 0, stream>>>(x, Wcb, bcomp, w_blk, wt_blk, xt_blk);
  k2_S<<<dim3(K2_PARTS, 4, B_), 512, 0, stream>>>(wt_blk, xt_blk, P, norm);
  k2r_reduce<<<dim3(B_ * HM_ * DIN_ / 4 / 256), 256, 0, stream>>>(P, S);
  k3a_st<<<dim3(8, H_, B_), 256, 0, stream>>>(S, Wfx, bfx, norm, st);
  k3b_attn<<<dim3(H_, B_), 256, 0, stream>>>(st, Wq, Wk, Wv, os);
  k3c_ct<<<dim3(64, B_), 256, 0, stream>>>(os, Wout, Ct_blk);
  k4_out<<<dim3(N_ / 128, DIN_ / 256, B_), 512, 0, stream>>>(w_blk, Ct_blk, bout, out);
}

// Round 14
// 439.075 us; speedup vs baseline: 1.1514x; 1.0221x over previous
//
#include <hip/hip_runtime.h>

#define B_ 4
#define N_ 16384
#define DIN_ 512
#define H_ 8
#define DH_ 64
#define M_ 32
#define HM_ 256
#define INNER_ 512
#define K2_PARTS 16
#define K2_NIT 32

typedef _Float16 fp16_t;
typedef _Float16 h8 __attribute__((ext_vector_type(8)));
typedef _Float16 h4 __attribute__((ext_vector_type(4)));
typedef float f4 __attribute__((ext_vector_type(4)));

// Fragment-blocked layout: a logical operand Q[R rows][K contraction] is stored as
// tiles of 16 rows x 32 k; tile -> 512 fp16; element (row, k) at lane*8+e where
// lane = (k%32/8)*16 + row%16, e = k%8. A wave reads one fragment as ONE h8 load
// at (tile_base + lane*8) -- perfectly coalesced 1KB, zero LDS, zero barriers.

// XOR swizzle of hm (in 8-elem groups) by n-group for the K1 epilogue LDS tile
__device__ __forceinline__ int swz(int n, int hm) {
  return ((((hm >> 3) ^ ((n >> 3) & 3)) << 3) | (hm & 7));
}

// XOR-swizzled element offset inside the K1 x-tile [64 rows][512 k] (16B-group swz;
// folds row>>3 so the xt column-gather spreads across banks).
__device__ __forceinline__ int xoff(int row, int k) {
  const int g = ((k >> 3) & 56) | (((k >> 3) ^ row ^ (row >> 3)) & 7);
  return row * 512 + (g << 3) + (k & 7);
}

// ---------------- K0: composite logit weights, emitted FRAGMENT-BLOCKED -------------
// v2: parallelized 8 -> 128 blocks (grid (H,16), 16 k-chunks of 32). The 8-block
// original cost ~60us of pure serial latency (R13: -55us total).
__global__ __launch_bounds__(256) void k0_prep(
    const float* __restrict__ Wx, const float* __restrict__ bx,
    const float* __restrict__ Wslice, const float* __restrict__ bslice,
    const float* __restrict__ temperature,
    fp16_t* __restrict__ Wcb, float* __restrict__ bcomp) {
  __shared__ float ws[M_ * DH_];
  const int h = blockIdx.x;
  const int kc = blockIdx.y;                  // k-chunk of 32
  const int tid = threadIdx.x;
  for (int i = tid; i < M_ * DH_; i += 256) ws[i] = Wslice[i];
  __syncthreads();
  const float invt = 1.0f / temperature[h];
  #pragma unroll
  for (int j = 0; j < 4; ++j) {
    const int idx = tid + j * 256;            // 0..1023 = 32 m x 32 k
    const int m = idx >> 5;
    const int k = kc * 32 + (idx & 31);
    const int hm = h * M_ + m;
    float acc = 0.f;
    #pragma unroll 16
    for (int d = 0; d < DH_; ++d)
      acc += ws[m * DH_ + d] * Wx[(size_t)(h * DH_ + d) * DIN_ + k];
    const int tile = (k >> 5) * 16 + (hm >> 4);
    const int ln = (((k >> 3) & 3) << 4) + (hm & 15);
    Wcb[(size_t)tile * 512 + ln * 8 + (k & 7)] = (fp16_t)(acc * invt);
  }
  if (kc == 0 && tid < M_) {
    const int m = tid;
    float acc = bslice[m];
    for (int d = 0; d < DH_; ++d) acc += ws[m * DH_ + d] * bx[h * DH_ + d];
    bcomp[h * M_ + m] = acc * invt;
  }
}

// ---------------- K1: logits GEMM + softmax; emits w_blk, wt_blk, xt_blk ------------
// v4 (best verified, R8/R11/R13): 512 threads / 8 waves; 64KB x-tile staged once
// (batch loads); barrier-free k-loop unrolled x2 with depth-2 Wcb prefetch.
__global__ __launch_bounds__(512) void k1_logits(
    const float* __restrict__ x, const fp16_t* __restrict__ Wcb,
    const float* __restrict__ bcomp, fp16_t* __restrict__ w_blk,
    fp16_t* __restrict__ wt_blk, fp16_t* __restrict__ xt_blk) {
  __shared__ __align__(16) fp16_t smem[64 * 512];   // 65536 B; x-tile, later lt
  fp16_t* lt = smem;            // [64 n][264 hm-swizzled] epilogue tile (aliases x-tile)
  const int tid = threadIdx.x;
  const int lane = tid & 63;
  const int wv = tid >> 6;                      // 0..7
  const int n0 = blockIdx.x * 64;
  const int b = blockIdx.y;
  f4 acc[4][2] = {};
  const float* xb = x + ((size_t)b * N_ + n0) * DIN_;
  const int lrow = lane & 15;
  const int kgq = lane >> 4;                    // k-subgroup 0..3
  // xt-pass constants: waves 0..3 own chunk (rt, nt) of the 32k x 64n iter tile
  const int xt_rt = wv >> 1;                    // 0..1  (k sub-tile of 16)
  const int xt_nt = wv & 1;                     // 0..1  (n sub-tile of 32)
  const int xt_k = xt_rt * 16 + (lane & 15);
  const int xt_nb = xt_nt * 32 + (lane >> 4) * 8;
  const fp16_t* wp = Wcb + (size_t)(wv * 2) * 512 + lane * 8;  // + (kt*16+t)*512

  // ---- stage the whole x tile: batch-issue all 16 global loads, then convert ----
  f4 xv[16];
  #pragma unroll
  for (int i = 0; i < 16; ++i) {
    const int fid = tid + i * 512;
    xv[i] = *(const f4*)(xb + (size_t)(fid >> 7) * DIN_ + (fid & 127) * 4);
  }
  #pragma unroll
  for (int i = 0; i < 16; ++i) {
    const int fid = tid + i * 512;
    h4 hv = {(fp16_t)xv[i].x, (fp16_t)xv[i].y, (fp16_t)xv[i].z, (fp16_t)xv[i].w};
    *(h4*)&smem[xoff(fid >> 7, (fid & 127) * 4)] = hv;
  }
  h8 bfA[2], bfB[2];
  #pragma unroll
  for (int t = 0; t < 2; ++t) {
    bfA[t] = *(const h8*)(wp + (size_t)t * 512);            // kt = 0
    bfB[t] = *(const h8*)(wp + (size_t)(16 + t) * 512);     // kt = 1
  }
  __syncthreads();

  // ---- barrier-free MFMA k-loop, unrolled x2, Wcb prefetch depth 2 ----
  for (int kt = 0; kt < 16; kt += 2) {
    // even iter (kt) uses bfA
    if (wv < 4) {
      h8 tx;
      #pragma unroll
      for (int e = 0; e < 8; ++e)
        tx[e] = smem[xoff(xt_nb + e, kt * 32 + xt_k)];
      *(h8*)(xt_blk + (((size_t)(b * 32 + kt * 2 + xt_rt) * (N_ / 32)) + (n0 >> 5) + xt_nt) * 512 + lane * 8) = tx;
    }
    {
      h8 af[4];
      #pragma unroll
      for (int t = 0; t < 4; ++t)
        af[t] = *(const h8*)&smem[xoff(t * 16 + lrow, kt * 32 + kgq * 8)];
      #pragma unroll
      for (int tn = 0; tn < 4; ++tn)
        #pragma unroll
        for (int tc = 0; tc < 2; ++tc)
          acc[tn][tc] = __builtin_amdgcn_mfma_f32_16x16x32_f16(af[tn], bfA[tc], acc[tn][tc], 0, 0, 0);
    }
    if (kt + 2 < 16) {
      #pragma unroll
      for (int t = 0; t < 2; ++t)
        bfA[t] = *(const h8*)(wp + (size_t)((kt + 2) * 16 + t) * 512);
    }
    // odd iter (kt+1) uses bfB
    if (wv < 4) {
      h8 tx;
      #pragma unroll
      for (int e = 0; e < 8; ++e)
        tx[e] = smem[xoff(xt_nb + e, (kt + 1) * 32 + xt_k)];
      *(h8*)(xt_blk + (((size_t)(b * 32 + (kt + 1) * 2 + xt_rt) * (N_ / 32)) + (n0 >> 5) + xt_nt) * 512 + lane * 8) = tx;
    }
    {
      h8 af[4];
      #pragma unroll
      for (int t = 0; t < 4; ++t)
        af[t] = *(const h8*)&smem[xoff(t * 16 + lrow, (kt + 1) * 32 + kgq * 8)];
      #pragma unroll
      for (int tn = 0; tn < 4; ++tn)
        #pragma unroll
        for (int tc = 0; tc < 2; ++tc)
          acc[tn][tc] = __builtin_amdgcn_mfma_f32_16x16x32_f16(af[tn], bfB[tc], acc[tn][tc], 0, 0, 0);
    }
    if (kt + 3 < 16) {
      #pragma unroll
      for (int t = 0; t < 2; ++t)
        bfB[t] = *(const h8*)(wp + (size_t)((kt + 3) * 16 + t) * 512);
    }
  }
  __syncthreads();   // all x-tile reads done before lt reuse

  // ---- epilogue: bias-add, dump logits to LDS tile [n][hm] (swizzled) ----
  const int col = lane & 15;
  const int rgrp = (lane >> 4) * 4;
  const float bc0 = bcomp[wv * 32 + col];
  const float bc1 = bcomp[wv * 32 + 16 + col];
  const int hmA = wv * 32 + col;
  #pragma unroll
  for (int tn = 0; tn < 4; ++tn)
    #pragma unroll
    for (int r = 0; r < 4; ++r) {
      const int nl = tn * 16 + rgrp + r;
      lt[nl * 264 + swz(nl, hmA)] = (fp16_t)(acc[tn][0][r] + bc0);
      lt[nl * 264 + swz(nl, hmA + 16)] = (fp16_t)(acc[tn][1][r] + bc1);
    }
  __syncthreads();

  // ---- softmax: each thread owns one (n, head) row of 32 logits ----
  {
    const int nl = tid >> 3, h = tid & 7;
    const int sw = (nl >> 3) & 3;
    h8 ch[4];
    #pragma unroll
    for (int q = 0; q < 4; ++q)
      ch[q] = *(const h8*)&lt[nl * 264 + ((h * 4 + q) ^ sw) * 8];
    float v[32];
    #pragma unroll
    for (int q = 0; q < 4; ++q)
      #pragma unroll
      for (int e = 0; e < 8; ++e) v[q * 8 + e] = (float)ch[q][e];
    float mx = v[0];
    #pragma unroll
    for (int j = 1; j < 32; ++j) mx = fmaxf(mx, v[j]);
    float sm = 0.f;
    #pragma unroll
    for (int j = 0; j < 32; ++j) { v[j] = __expf(v[j] - mx); sm += v[j]; }
    const float inv = __builtin_amdgcn_rcpf(sm);
    h8 oc[4];
    #pragma unroll
    for (int q = 0; q < 4; ++q)
      #pragma unroll
      for (int e = 0; e < 8; ++e) oc[q][e] = (fp16_t)(v[q * 8 + e] * inv);
    #pragma unroll
    for (int q = 0; q < 4; ++q)
      *(h8*)&lt[nl * 264 + ((h * 4 + q) ^ sw) * 8] = oc[q];
  }
  __syncthreads();

  // ---- w_blk pass: contiguous h8 LDS reads -> blocked global (K4 A layout) ----
  #pragma unroll
  for (int p = 0; p < 4; ++p) {
    const int tile = p * 8 + wv;          // 0..31 = 4 ntiles x 8 hmblks
    const int nt_l = tile >> 3, hmb = tile & 7;
    const int n_l = nt_l * 16 + (lane & 15);
    const int g = hmb * 4 + (lane >> 4);
    const int sw = (n_l >> 3) & 3;
    h8 v = *(const h8*)&lt[n_l * 264 + (g ^ sw) * 8];
    *(h8*)(w_blk + (((size_t)(b * (N_ / 16) + (n0 >> 4) + nt_l)) * 8 + hmb) * 512 + lane * 8) = v;
  }

  // ---- wt_blk pass: strided LDS gather -> blocked global (K2 A layout) ----
  #pragma unroll
  for (int p = 0; p < 4; ++p) {
    const int tile = p * 8 + wv;          // 0..31 = 16 hmtiles x 2 ntiles
    const int hmt = tile >> 1, ntl = tile & 1;
    const int hm = hmt * 16 + (lane & 15);
    const int nb = ntl * 32 + (lane >> 4) * 8;
    h8 v;
    #pragma unroll
    for (int e = 0; e < 8; ++e) {
      const int n = nb + e;
      v[e] = lt[n * 264 + swz(n, hm)];
    }
    *(h8*)(wt_blk + (((size_t)(b * 16 + hmt)) * (N_ / 32) + (n0 >> 5) + ntl) * 512 + lane * 8) = v;
  }
}

// ---------------- K2: P[part,b,hm,k] = partial sum_n w^T x — no atomics -------------
// v2 body (best verified, R8); grid TRANSPOSED to (part, combo, b) so blocks
// sharing wt rows (dID +32) and xt rows (dID +16) round-robin onto the SAME XCD
// (delta % 8 == 0) -> second read hits local L2.
__global__ __launch_bounds__(512) void k2_S(
    const fp16_t* __restrict__ wt_blk, const fp16_t* __restrict__ xt_blk,
    float* __restrict__ P, float* __restrict__ norm) {
  const int tid = threadIdx.x, lane = tid & 63, wv = tid >> 6;   // wv 0..7
  const int part = blockIdx.x;
  const int hm0 = (blockIdx.y & 1) * 128;
  const int kc0 = (blockIdx.y >> 1) * 256;
  const int nt0 = part * K2_NIT;              // K2_NIT n-tiles of 32 per block
  const int b = blockIdx.z;
  const int hmw = (wv & 1) * 64, kw = (wv >> 1) * 64;   // kw 0..192
  const int hmt0 = (hm0 + hmw) >> 4;
  const int kt0 = (kc0 + kw) >> 4;
  const fp16_t* ap = wt_blk + (((size_t)(b * 16 + hmt0)) * (N_ / 32) + nt0) * 512 + lane * 8;
  const fp16_t* bp = xt_blk + (((size_t)(b * 32 + kt0)) * (N_ / 32) + nt0) * 512 + lane * 8;
  const size_t arow = (size_t)(N_ / 32) * 512;  // stride between row-tiles
  f4 acc[4][4] = {};
  float ns[4] = {0.f, 0.f, 0.f, 0.f};
  const bool do_norm = (kc0 == 0) && (kw == 0);

  h8 aA[4], bA[4], aB[4], bB[4];
  #pragma unroll
  for (int t = 0; t < 4; ++t) {
    aA[t] = *(const h8*)(ap + (size_t)t * arow);
    bA[t] = *(const h8*)(bp + (size_t)t * arow);
  }
  for (int it = 0; it < K2_NIT; it += 2) {
    #pragma unroll
    for (int t = 0; t < 4; ++t) {
      aB[t] = *(const h8*)(ap + (size_t)t * arow + (it + 1) * 512);
      bB[t] = *(const h8*)(bp + (size_t)t * arow + (it + 1) * 512);
    }
    #pragma unroll
    for (int tn = 0; tn < 4; ++tn)
      #pragma unroll
      for (int tc = 0; tc < 4; ++tc)
        acc[tn][tc] = __builtin_amdgcn_mfma_f32_16x16x32_f16(aA[tn], bA[tc], acc[tn][tc], 0, 0, 0);
    if (do_norm) {
      #pragma unroll
      for (int t = 0; t < 4; ++t)
        #pragma unroll
        for (int e = 0; e < 8; ++e) ns[t] += (float)aA[t][e];
    }
    if (it + 2 < K2_NIT) {
      #pragma unroll
      for (int t = 0; t < 4; ++t) {
        aA[t] = *(const h8*)(ap + (size_t)t * arow + (it + 2) * 512);
        bA[t] = *(const h8*)(bp + (size_t)t * arow + (it + 2) * 512);
      }
    }
    #pragma unroll
    for (int tn = 0; tn < 4; ++tn)
      #pragma unroll
      for (int tc = 0; tc < 4; ++tc)
        acc[tn][tc] = __builtin_amdgcn_mfma_f32_16x16x32_f16(aB[tn], bB[tc], acc[tn][tc], 0, 0, 0);
    if (do_norm) {
      #pragma unroll
      for (int t = 0; t < 4; ++t)
        #pragma unroll
        for (int e = 0; e < 8; ++e) ns[t] += (float)aB[t][e];
    }
  }

  if (do_norm) {
    #pragma unroll
    for (int t = 0; t < 4; ++t) {
      ns[t] += __shfl_xor(ns[t], 16);
      ns[t] += __shfl_xor(ns[t], 32);
    }
    if (lane < 16) {
      #pragma unroll
      for (int t = 0; t < 4; ++t)
        atomicAdd(&norm[b * HM_ + (hmt0 + t) * 16 + lane], ns[t]);
    }
  }
  // plain stores to the partials buffer (this block exclusively owns its cells)
  float* Pp = P + (((size_t)part * B_ + b) * HM_ + hm0 + hmw) * DIN_ + kc0 + kw;
  const int rg = (lane >> 4) * 4;
  #pragma unroll
  for (int tn = 0; tn < 4; ++tn)
    #pragma unroll
    for (int tc = 0; tc < 4; ++tc)
      #pragma unroll
      for (int r = 0; r < 4; ++r)
        Pp[(size_t)(tn * 16 + rg + r) * DIN_ + tc * 16 + (lane & 15)] = acc[tn][tc][r];
}

// ---------------- K2r: S = sum over 16 parts of P -----------------------------------
__global__ __launch_bounds__(256) void k2r_reduce(
    const float* __restrict__ P, float* __restrict__ S) {
  const size_t idx = (size_t)blockIdx.x * 256 + threadIdx.x;   // f4 index
  const f4* P4 = (const f4*)P;
  f4 a = P4[idx];
  #pragma unroll
  for (int p = 1; p < K2_PARTS; ++p)
    a += P4[(size_t)p * (B_ * HM_ * DIN_ / 4) + idx];
  ((f4*)S)[idx] = a;
}

// ---------------- K3a: slice_token[b,h,m,d] = (S.Wfx + bfx*norm)/(norm+1e-5) --------
__global__ __launch_bounds__(256) void k3a_st(
    const float* __restrict__ S, const float* __restrict__ Wfx,
    const float* __restrict__ bfx, const float* __restrict__ norm,
    float* __restrict__ st) {
  const int mq = blockIdx.x;
  const int h = blockIdx.y;
  const int b = blockIdx.z;
  const int tid = threadIdx.x;
  const int m = mq * 4 + (tid >> 6);
  const int d = tid & 63;
  const float* sr = S + ((size_t)b * HM_ + h * M_ + m) * DIN_;
  const float* wr = Wfx + (size_t)(h * DH_ + d) * DIN_;
  float acc = 0.f;
  #pragma unroll 8
  for (int k = 0; k < DIN_; k += 4) {
    f4 a = *(const f4*)(sr + k);
    f4 bb = *(const f4*)(wr + k);
    acc += a.x * bb.x + a.y * bb.y + a.z * bb.z + a.w * bb.w;
  }
  const float nr = norm[b * HM_ + h * M_ + m];
  st[(((size_t)b * H_ + h) * M_ + m) * DH_ + d] =
      (acc + bfx[h * DH_ + d] * nr) / (nr + 1e-5f);
}

// ---------------- K3b: tiny M=32 attention per (b,h) --------------------------------
// v2: 1024 threads (16 waves) — the 256-thread/32-block version was the last
// small-grid latency kernel in the chain (k0 lesson, R13).
__global__ __launch_bounds__(1024) void k3b_attn(
    const float* __restrict__ st_g, const float* __restrict__ Wq,
    const float* __restrict__ Wk, const float* __restrict__ Wv,
    float* __restrict__ os_g) {
  __shared__ float st[32][65], qs[32][65], ks[32][65], vs[32][65], at[32][33];
  const int h = blockIdx.x, b = blockIdx.y, tid = threadIdx.x;
  const float* stp = st_g + ((size_t)b * H_ + h) * M_ * DH_;
  for (int i = tid; i < 2048; i += 1024) st[i >> 6][i & 63] = stp[i];
  __syncthreads();
  for (int i = tid; i < 2048; i += 1024) {
    const int m = i >> 6, d = i & 63;
    float aq = 0, ak = 0, av = 0;
    #pragma unroll 8
    for (int dd = 0; dd < 64; ++dd) {
      const float s = st[m][dd];
      aq += s * Wq[d * 64 + dd];
      ak += s * Wk[d * 64 + dd];
      av += s * Wv[d * 64 + dd];
    }
    qs[m][d] = aq; ks[m][d] = ak; vs[m][d] = av;
  }
  __syncthreads();
  if (tid < 1024) {
    const int m = tid >> 5, j = tid & 31;
    float a = 0;
    #pragma unroll 8
    for (int d = 0; d < 64; ++d) a += qs[m][d] * ks[j][d];
    at[m][j] = a * 0.125f;
  }
  __syncthreads();
  if (tid < 32) {
    const int m = tid;
    float mx = -1e30f;
    for (int j = 0; j < 32; ++j) mx = fmaxf(mx, at[m][j]);
    float sm = 0;
    for (int j = 0; j < 32; ++j) { const float e = __expf(at[m][j] - mx); at[m][j] = e; sm += e; }
    const float inv = 1.0f / sm;
    for (int j = 0; j < 32; ++j) at[m][j] *= inv;
  }
  __syncthreads();
  float* osp = os_g + ((size_t)b * H_ + h) * M_ * DH_;
  for (int i = tid; i < 2048; i += 1024) {
    const int m = i >> 6, d = i & 63;
    float a = 0;
    #pragma unroll 8
    for (int j = 0; j < 32; ++j) a += at[m][j] * vs[j][d];
    osp[i] = a;
  }
}

// ---------------- K3c: Ct_blk[b][kkt=32][hmb=8][512]  (K4 B-operand layout) ---------
__global__ __launch_bounds__(256) void k3c_ct(
    const float* __restrict__ os_g, const float* __restrict__ Wout,
    fp16_t* __restrict__ Ct_blk) {
  const int tid = threadIdx.x, lane = tid & 63, wv = tid >> 6;
  const int b = blockIdx.y;
  const int ti = blockIdx.x * 4 + wv;     // 0..255 tiles
  const int kkt = ti >> 3, hmb = ti & 7;
  const int kk = kkt * 16 + (lane & 15);
  h8 outv;
  #pragma unroll
  for (int e = 0; e < 8; ++e) {
    const int hm = hmb * 32 + (lane >> 4) * 8 + e;
    const int h = hm >> 5, m = hm & 31;
    const float* op = os_g + (((size_t)b * H_ + h) * M_ + m) * DH_;
    const float* wp = Wout + (size_t)kk * INNER_ + h * DH_;
    float acc = 0.f;
    #pragma unroll
    for (int d = 0; d < 64; d += 4) {
      f4 a = *(const f4*)(op + d);
      f4 w4 = *(const f4*)(wp + d);
      acc += a.x * w4.x + a.y * w4.y + a.z * w4.z + a.w * w4.w;
    }
    outv[e] = (fp16_t)acc;
  }
  *(h8*)(Ct_blk + (((size_t)(b * 32 + kkt)) * 8 + hmb) * 512 + lane * 8) = outv;
}

// ---------------- K4: out = w . Ct^T + bout — streaming MFMA ------------------------
// v2 body (best verified, R8); grid TRANSPOSED to (n, kk, b) so the two blocks
// sharing each w_blk panel differ by dID=128 (==0 mod 8) -> same XCD L2.
__global__ __launch_bounds__(512) void k4_out(
    const fp16_t* __restrict__ w_blk, const fp16_t* __restrict__ Ct_blk,
    const float* __restrict__ bout, float* __restrict__ out) {
  const int tid = threadIdx.x, lane = tid & 63, wv = tid >> 6;   // wv 0..7
  const int n0 = blockIdx.x * 128;
  const int kk0 = blockIdx.y * 256;
  const int b = blockIdx.z;
  const int nh = (wv & 1) * 64, kh = (wv >> 1) * 64;   // kh 0..192
  const int nt0 = (n0 + nh) >> 4;
  const int kkt0 = (kk0 + kh) >> 4;
  const fp16_t* ap = w_blk + ((size_t)(b * (N_ / 16) + nt0)) * 8 * 512 + lane * 8;
  const fp16_t* bp = Ct_blk + ((size_t)(b * 32 + kkt0)) * 8 * 512 + lane * 8;
  f4 acc[4][4] = {};

  #pragma unroll
  for (int hmb = 0; hmb < 8; ++hmb) {
    h8 af[4], bf[4];
    #pragma unroll
    for (int t = 0; t < 4; ++t) af[t] = *(const h8*)(ap + (size_t)t * 8 * 512 + hmb * 512);
    #pragma unroll
    for (int t = 0; t < 4; ++t) bf[t] = *(const h8*)(bp + (size_t)t * 8 * 512 + hmb * 512);
    #pragma unroll
    for (int tn = 0; tn < 4; ++tn)
      #pragma unroll
      for (int tc = 0; tc < 4; ++tc)
        acc[tn][tc] = __builtin_amdgcn_mfma_f32_16x16x32_f16(af[tn], bf[tc], acc[tn][tc], 0, 0, 0);
  }
  const int rg = (lane >> 4) * 4;
  #pragma unroll
  for (int tc = 0; tc < 4; ++tc) {
    const int kk = kk0 + kh + tc * 16 + (lane & 15);
    const float bo = bout[kk];
    #pragma unroll
    for (int tn = 0; tn < 4; ++tn)
      #pragma unroll
      for (int r = 0; r < 4; ++r) {
        const int n = n0 + nh + tn * 16 + rg + r;
        out[((size_t)b * N_ + n) * DIN_ + kk] = acc[tn][tc][r] + bo;
      }
  }
}

extern "C" void kernel_launch(void* const* d_in, const int* in_sizes, int n_in,
                              void* d_out, int out_size, void* d_ws, size_t ws_size,
                              hipStream_t stream) {
  (void)in_sizes; (void)n_in; (void)out_size; (void)ws_size;
  const float* x       = (const float*)d_in[0];
  const float* Wx      = (const float*)d_in[1];
  const float* bx      = (const float*)d_in[2];
  const float* Wfx     = (const float*)d_in[3];
  const float* bfx     = (const float*)d_in[4];
  const float* Wslice  = (const float*)d_in[5];
  const float* bslice  = (const float*)d_in[6];
  const float* Wq      = (const float*)d_in[7];
  const float* Wk      = (const float*)d_in[8];
  const float* Wv      = (const float*)d_in[9];
  const float* Wout    = (const float*)d_in[10];
  const float* bout    = (const float*)d_in[11];
  const float* temp    = (const float*)d_in[12];
  float* out = (float*)d_out;

  char* ws = (char*)d_ws;
  fp16_t* w_blk  = (fp16_t*)ws;                    //  33,554,432 : w  blocked (K4-A)
  fp16_t* wt_blk = (fp16_t*)(ws + 33554432);       //  33,554,432 : w^T blocked (K2-A)
  fp16_t* xt_blk = (fp16_t*)(ws + 67108864);       //  67,108,864 : x^T fp16 blocked (K2-B)
  float*  S      = (float*)(ws + 134217728);       //   2,097,152
  float*  norm   = (float*)(ws + 136314880);       //       4,096
  float*  st     = (float*)(ws + 136318976);       //     262,144
  float*  os     = (float*)(ws + 136581120);       //     262,144
  fp16_t* Ct_blk = (fp16_t*)(ws + 136843264);      //   1,048,576
  fp16_t* Wcb    = (fp16_t*)(ws + 137891840);      //     262,144 : Wcomp fragment-blocked
  float*  bcomp  = (float*)(ws + 138153984);       //       4,096 (1KB used)
  float*  P      = (float*)(ws + 138158080);       //  33,554,432 : K2 fp32 partials

  hipMemsetAsync(norm, 0, (size_t)B_ * HM_ * 4, stream);
  k0_prep<<<dim3(H_, 16), 256, 0, stream>>>(Wx, bx, Wslice, bslice, temp, Wcb, bcomp);
  k1_logits<<<dim3(N_ / 64, B_), 512, 0, stream>>>(x, Wcb, bcomp, w_blk, wt_blk, xt_blk);
  k2_S<<<dim3(K2_PARTS, 4, B_), 512, 0, stream>>>(wt_blk, xt_blk, P, norm);
  k2r_reduce<<<dim3(B_ * HM_ * DIN_ / 4 / 256), 256, 0, stream>>>(P, S);
  k3a_st<<<dim3(8, H_, B_), 256, 0, stream>>>(S, Wfx, bfx, norm, st);
  k3b_attn<<<dim3(H_, B_), 1024, 0, stream>>>(st, Wq, Wk, Wv, os);
  k3c_ct<<<dim3(64, B_), 256, 0, stream>>>(os, Wout, Ct_blk);
  k4_out<<<dim3(N_ / 128, DIN_ / 256, B_), 512, 0, stream>>>(w_blk, Ct_blk, bout, out);
}